// Round 2
// baseline (1482.559 us; speedup 1.0000x reference)
//
#include <hip/hip_runtime.h>

#define NN 100000
#define NE 3200000
#define CAP 6144
#define NBUCK 782   // ceil(NN/128)

typedef __attribute__((ext_vector_type(8))) short bf16x8;
typedef __attribute__((ext_vector_type(4))) float f32x4;

__device__ __forceinline__ ushort f2bf(float f) {
  unsigned u = __builtin_bit_cast(unsigned, f);
  u = (u + 0x7FFFu + ((u >> 16) & 1u)) >> 16;
  return (ushort)u;
}
__device__ __forceinline__ float bf2f(ushort h) {
  return __builtin_bit_cast(float, ((unsigned)h) << 16);
}
__device__ __forceinline__ void gl2lds16(const void* g, void* s) {
  __builtin_amdgcn_global_load_lds((const __attribute__((address_space(1))) void*)g,
                                   (__attribute__((address_space(3))) void*)s, 16, 0, 0);
}

// ---------------- CSR build: bucketed counting sort ----------------
// Phase A: append edges to 782 coarse buckets (row>>7). Appends are dense ->
// write amplification ~1 (vs 8x for full random scatter).
__global__ __launch_bounds__(256) void k_bucket(const int* __restrict__ row, const int* __restrict__ col,
                                                const float* __restrict__ w, int* __restrict__ bcnt,
                                                int2* __restrict__ bdata) {
  int i = (blockIdx.x * 256 + threadIdx.x) * 4;
  int4 r = *(const int4*)(row + i);
  int4 c = *(const int4*)(col + i);
  float4 ww = *(const float4*)(w + i);
  int b, p;
  b = r.x >> 7; p = atomicAdd(&bcnt[b], 1);
  if (p < CAP) bdata[(size_t)b * CAP + p] = make_int2(((r.x & 127) << 17) | c.x, __float_as_int(ww.x));
  b = r.y >> 7; p = atomicAdd(&bcnt[b], 1);
  if (p < CAP) bdata[(size_t)b * CAP + p] = make_int2(((r.y & 127) << 17) | c.y, __float_as_int(ww.y));
  b = r.z >> 7; p = atomicAdd(&bcnt[b], 1);
  if (p < CAP) bdata[(size_t)b * CAP + p] = make_int2(((r.z & 127) << 17) | c.z, __float_as_int(ww.z));
  b = r.w >> 7; p = atomicAdd(&bcnt[b], 1);
  if (p < CAP) bdata[(size_t)b * CAP + p] = make_int2(((r.w & 127) << 17) | c.w, __float_as_int(ww.w));
}

// scan of 782 bucket counts -> bucket bases (one small block)
__global__ __launch_bounds__(1024) void k_bscan(const int* __restrict__ bcnt, int* __restrict__ bbase) {
  __shared__ int s[1024];
  int t = threadIdx.x;
  s[t] = (t < NBUCK) ? bcnt[t] : 0;
  __syncthreads();
  for (int o = 1; o < 1024; o <<= 1) {
    int v = (t >= o) ? s[t - o] : 0;
    __syncthreads();
    s[t] += v;
    __syncthreads();
  }
  if (t < NBUCK) bbase[t] = t ? s[t - 1] : 0;
}

// Phase B: one block per bucket. LDS 128-row hist + scan -> rp directly,
// then scatter into final cw (contiguous ~32KB region, L2-resident).
__global__ __launch_bounds__(256) void k_bsort(const int* __restrict__ bcnt, const int* __restrict__ bbase,
                                               const int2* __restrict__ bdata, int2* __restrict__ cw,
                                               int* __restrict__ rp) {
  __shared__ int sc[128], lpos[128];
  int b = blockIdx.x, t = threadIdx.x;
  int n = bcnt[b], base = bbase[b];
  if (t < 128) sc[t] = 0;
  __syncthreads();
  for (int i = t; i < n; i += 256) {
    int r = bdata[(size_t)b * CAP + i].x >> 17;
    atomicAdd(&sc[r], 1);
  }
  __syncthreads();
  // inclusive Hillis-Steele over 128
  for (int o = 1; o < 128; o <<= 1) {
    int v = (t < 128 && t >= o) ? sc[t - o] : 0;
    __syncthreads();
    if (t < 128) sc[t] += v;
    __syncthreads();
  }
  if (t < 128) {
    int excl = t ? sc[t - 1] : 0;
    lpos[t] = excl;
    int grow = b * 128 + t;
    if (grow <= NN) rp[grow] = base + excl;  // bucket 781, t=32 writes rp[NN]=NE
  }
  __syncthreads();
  for (int i = t; i < n; i += 256) {
    int2 e = bdata[(size_t)b * CAP + i];
    int r = e.x >> 17;
    int p = atomicAdd(&lpos[r], 1);
    cw[base + p] = make_int2(e.x & 0x1FFFF, e.y);
  }
}

// ---------------- weight prep: fold BN, transpose to [N][K], cast bf16 ----------------
__global__ __launch_bounds__(256) void k_prep(const float* __restrict__ W, const float* __restrict__ b,
                                              const float* __restrict__ g, const float* __restrict__ be,
                                              const float* __restrict__ m, const float* __restrict__ v,
                                              ushort* __restrict__ Wt, float* __restrict__ bp, int Ncol) {
  int j = blockIdx.x, k = threadIdx.x;
  float val = 0.f;
  if (j < Ncol) {
    float s = 1.f, t = 0.f;
    if (g) { s = g[j] * rsqrtf(v[j] + 1e-5f); t = be[j] - m[j] * s; }
    val = W[(size_t)k * Ncol + j] * s;
    if (k == 0) bp[j] = b[j] * s + t;
  } else if (k == 0) bp[j] = 0.f;
  Wt[(size_t)j * 256 + k] = f2bf(val);
}

// ---------------- x fp32 -> bf16 ----------------
__global__ __launch_bounds__(256) void k_f2bf8(const float* __restrict__ x, ushort* __restrict__ o) {
  size_t i = ((size_t)blockIdx.x * 256 + threadIdx.x) * 8;
  float4 u = *(const float4*)(x + i);
  float4 v = *(const float4*)(x + i + 4);
  ushort4 r0; r0.x = f2bf(u.x); r0.y = f2bf(u.y); r0.z = f2bf(u.z); r0.w = f2bf(u.w);
  ushort4 r1; r1.x = f2bf(v.x); r1.y = f2bf(v.y); r1.z = f2bf(v.z); r1.w = f2bf(v.w);
  *(ushort4*)(o + i) = r0;
  *(ushort4*)(o + i + 4) = r1;
}

// ---------------- bf16 MFMA GEMM: C[M x ncst] = A[M x 256] @ Wt^T, + bias, bf16 out ----------------
__global__ __launch_bounds__(256) void k_gemm(const ushort* __restrict__ A, const ushort* __restrict__ Bt,
                                              const float* __restrict__ bp, ushort* __restrict__ C,
                                              int M, int ldc, int ncst) {
  __shared__ ushort sA[128 * 64];
  __shared__ ushort sB[128 * 64];
  const int tid = threadIdx.x;
  const int lane = tid & 63;
  const int wave = tid >> 6;
  const int wm = wave >> 1, wn = wave & 1;
  const int bm = blockIdx.x, bn = blockIdx.y;

  f32x4 acc[4][4];
#pragma unroll
  for (int a = 0; a < 4; ++a)
#pragma unroll
    for (int b = 0; b < 4; ++b) acc[a][b] = (f32x4){0.f, 0.f, 0.f, 0.f};

  const char* Ab = (const char*)A;
  const char* Bb = (const char*)Bt;
  char* sAb = (char*)sA;
  char* sBb = (char*)sB;

  for (int kt = 0; kt < 4; ++kt) {
#pragma unroll
    for (int it = 0; it < 4; ++it) {
      int o = tid * 16 + it * 4096;
      int r = o >> 7, kb = o & 127;
      int ra = bm * 128 + r; if (ra >= M) ra = M - 1;
      gl2lds16(Ab + (size_t)ra * 512 + kt * 128 + kb, sAb + o);
      gl2lds16(Bb + (size_t)(bn * 128 + r) * 512 + kt * 128 + kb, sBb + o);
    }
    __syncthreads();
#pragma unroll
    for (int kk = 0; kk < 2; ++kk) {
      int kByte = kk * 64 + ((lane >> 4) << 4);
      bf16x8 af[4], bfr[4];
#pragma unroll
      for (int mi = 0; mi < 4; ++mi)
        af[mi] = *(const bf16x8*)(sAb + (wm * 64 + mi * 16 + (lane & 15)) * 128 + kByte);
#pragma unroll
      for (int ni = 0; ni < 4; ++ni)
        bfr[ni] = *(const bf16x8*)(sBb + (wn * 64 + ni * 16 + (lane & 15)) * 128 + kByte);
#pragma unroll
      for (int mi = 0; mi < 4; ++mi)
#pragma unroll
        for (int ni = 0; ni < 4; ++ni)
          acc[mi][ni] = __builtin_amdgcn_mfma_f32_16x16x32_bf16(af[mi], bfr[ni], acc[mi][ni], 0, 0, 0);
    }
    __syncthreads();
  }

  const int r0 = bm * 128 + wm * 64 + ((lane >> 4) << 2);
  const int c0 = bn * 128 + wn * 64 + (lane & 15);
#pragma unroll
  for (int ni = 0; ni < 4; ++ni) {
    int col = c0 + ni * 16;
    if (col >= ncst) continue;
    float bpv = bp[col];
#pragma unroll
    for (int mi = 0; mi < 4; ++mi)
#pragma unroll
      for (int i = 0; i < 4; ++i) {
        int row = r0 + mi * 16 + i;
        if (row < M) C[(size_t)row * ldc + col] = f2bf(acc[mi][ni][i] + bpv);
      }
  }
}

// ---------------- SpMM 256-dim: Y[i,:] = relu(sum w_e * H[col_e,:]), one wave/node ----------------
__global__ __launch_bounds__(256) void k_spmm256(const int* __restrict__ rp, const int2* __restrict__ cw,
                                                 const ushort* __restrict__ H, ushort* __restrict__ Y) {
  int node = blockIdx.x * 4 + (threadIdx.x >> 6);
  int lane = threadIdx.x & 63;
  int s = rp[node], e = rp[node + 1];
  float a0 = 0.f, a1 = 0.f, a2 = 0.f, a3 = 0.f;
  const ushort* Hl = H + (lane << 2);
  int i = s;
  for (; i + 4 <= e; i += 4) {
    int2 p0 = cw[i], p1 = cw[i + 1], p2 = cw[i + 2], p3 = cw[i + 3];
    ushort4 h0 = *(const ushort4*)(Hl + (size_t)p0.x * 256);
    ushort4 h1 = *(const ushort4*)(Hl + (size_t)p1.x * 256);
    ushort4 h2 = *(const ushort4*)(Hl + (size_t)p2.x * 256);
    ushort4 h3 = *(const ushort4*)(Hl + (size_t)p3.x * 256);
    float w0 = __int_as_float(p0.y), w1 = __int_as_float(p1.y);
    float w2 = __int_as_float(p2.y), w3 = __int_as_float(p3.y);
    a0 += w0 * bf2f(h0.x); a1 += w0 * bf2f(h0.y); a2 += w0 * bf2f(h0.z); a3 += w0 * bf2f(h0.w);
    a0 += w1 * bf2f(h1.x); a1 += w1 * bf2f(h1.y); a2 += w1 * bf2f(h1.z); a3 += w1 * bf2f(h1.w);
    a0 += w2 * bf2f(h2.x); a1 += w2 * bf2f(h2.y); a2 += w2 * bf2f(h2.z); a3 += w2 * bf2f(h2.w);
    a0 += w3 * bf2f(h3.x); a1 += w3 * bf2f(h3.y); a2 += w3 * bf2f(h3.z); a3 += w3 * bf2f(h3.w);
  }
  for (; i < e; ++i) {
    int2 p = cw[i];
    ushort4 h = *(const ushort4*)(Hl + (size_t)p.x * 256);
    float w = __int_as_float(p.y);
    a0 += w * bf2f(h.x); a1 += w * bf2f(h.y); a2 += w * bf2f(h.z); a3 += w * bf2f(h.w);
  }
  a0 = fmaxf(a0, 0.f); a1 = fmaxf(a1, 0.f); a2 = fmaxf(a2, 0.f); a3 = fmaxf(a3, 0.f);
  ushort4 o;
  o.x = f2bf(a0); o.y = f2bf(a1); o.z = f2bf(a2); o.w = f2bf(a3);
  *(ushort4*)(Y + (size_t)node * 256 + (lane << 2)) = o;
}

// ---------------- SpMM 64-dim + fused log_softmax, fp32 out ----------------
__global__ __launch_bounds__(256) void k_spmm64(const int* __restrict__ rp, const int2* __restrict__ cw,
                                                const ushort* __restrict__ H, float* __restrict__ out) {
  int node = blockIdx.x * 4 + (threadIdx.x >> 6);
  int lane = threadIdx.x & 63;
  int s = rp[node], e = rp[node + 1];
  float a = 0.f;
  int i = s;
  for (; i + 4 <= e; i += 4) {
    int2 p0 = cw[i], p1 = cw[i + 1], p2 = cw[i + 2], p3 = cw[i + 3];
    float h0 = bf2f(H[(size_t)p0.x * 64 + lane]);
    float h1 = bf2f(H[(size_t)p1.x * 64 + lane]);
    float h2 = bf2f(H[(size_t)p2.x * 64 + lane]);
    float h3 = bf2f(H[(size_t)p3.x * 64 + lane]);
    a += __int_as_float(p0.y) * h0 + __int_as_float(p1.y) * h1
       + __int_as_float(p2.y) * h2 + __int_as_float(p3.y) * h3;
  }
  for (; i < e; ++i) {
    int2 p = cw[i];
    a += __int_as_float(p.y) * bf2f(H[(size_t)p.x * 64 + lane]);
  }
  float mx = a;
#pragma unroll
  for (int o = 32; o > 0; o >>= 1) mx = fmaxf(mx, __shfl_xor(mx, o, 64));
  float ex = expf(a - mx);
  float sum = ex;
#pragma unroll
  for (int o = 32; o > 0; o >>= 1) sum += __shfl_xor(sum, o, 64);
  out[(size_t)node * 64 + lane] = (a - mx) - logf(sum);
}

extern "C" void kernel_launch(void* const* d_in, const int* in_sizes, int n_in,
                              void* d_out, int out_size, void* d_ws, size_t ws_size,
                              hipStream_t stream) {
  const float* x   = (const float*)d_in[0];
  const int* erow  = (const int*)d_in[1];
  const int* ecol  = (const int*)d_in[2];
  const float* ew  = (const float*)d_in[3];
  const float* W1  = (const float*)d_in[4];
  const float* b1  = (const float*)d_in[5];
  const float* g1  = (const float*)d_in[6];
  const float* be1 = (const float*)d_in[7];
  const float* m1  = (const float*)d_in[8];
  const float* v1  = (const float*)d_in[9];
  const float* W2  = (const float*)d_in[10];
  const float* b2  = (const float*)d_in[11];
  const float* g2  = (const float*)d_in[12];
  const float* be2 = (const float*)d_in[13];
  const float* m2  = (const float*)d_in[14];
  const float* v2  = (const float*)d_in[15];
  const float* W3  = (const float*)d_in[16];
  const float* b3  = (const float*)d_in[17];

  char* ws = (char*)d_ws;
  size_t off = 0;
  auto carve = [&](size_t bytes) -> void* {
    void* p = ws + off;
    off += (bytes + 511) & ~(size_t)511;
    return p;
  };
  int* bcnt   = (int*)carve((size_t)NBUCK * 4);
  int* bbase  = (int*)carve((size_t)NBUCK * 4);
  int* rp     = (int*)carve((size_t)(NN + 1) * 4);
  int2* cw    = (int2*)carve((size_t)NE * 8);
  ushort* W1t = (ushort*)carve(256 * 256 * 2);
  ushort* W2t = (ushort*)carve(256 * 256 * 2);
  ushort* W3t = (ushort*)carve(128 * 256 * 2);
  float* bp1  = (float*)carve(256 * 4);
  float* bp2  = (float*)carve(256 * 4);
  float* bp3  = (float*)carve(128 * 4);
  ushort* bufA = (ushort*)carve((size_t)NN * 256 * 2);
  ushort* bufB = (ushort*)carve((size_t)NN * 256 * 2);
  ushort* bufC = (ushort*)carve((size_t)NN * 64 * 2);
  if (off > ws_size) return;

  // bucket scratch aliases bufA (not live until k_f2bf8): 782*6144*8B = 38.4MB <= 51.2MB
  int2* bdata = (int2*)bufA;

  // CSR build (bucketed counting sort)
  hipMemsetAsync(bcnt, 0, (size_t)NBUCK * 4, stream);
  k_bucket<<<NE / 1024, 256, 0, stream>>>(erow, ecol, ew, bcnt, bdata);
  k_bscan<<<1, 1024, 0, stream>>>(bcnt, bbase);
  k_bsort<<<NBUCK, 256, 0, stream>>>(bcnt, bbase, bdata, cw, rp);

  // weights (BN folded, transposed, bf16)
  k_prep<<<256, 256, 0, stream>>>(W1, b1, g1, be1, m1, v1, W1t, bp1, 256);
  k_prep<<<256, 256, 0, stream>>>(W2, b2, g2, be2, m2, v2, W2t, bp2, 256);
  k_prep<<<128, 256, 0, stream>>>(W3, b3, nullptr, nullptr, nullptr, nullptr, W3t, bp3, 64);

  // x -> bf16
  k_f2bf8<<<(NN * 256) / (256 * 8), 256, 0, stream>>>(x, bufA);

  const int gm = (NN + 127) / 128;
  // layer 1
  k_gemm<<<dim3(gm, 2), 256, 0, stream>>>(bufA, W1t, bp1, bufB, NN, 256, 256);
  k_spmm256<<<NN / 4, 256, 0, stream>>>(rp, cw, bufB, bufA);
  // layer 2
  k_gemm<<<dim3(gm, 2), 256, 0, stream>>>(bufA, W2t, bp2, bufB, NN, 256, 256);
  k_spmm256<<<NN / 4, 256, 0, stream>>>(rp, cw, bufB, bufA);
  // output layer
  k_gemm<<<dim3(gm, 1), 256, 0, stream>>>(bufA, W3t, bp3, bufC, NN, 64, 64);
  k_spmm64<<<NN / 4, 256, 0, stream>>>(rp, cw, bufC, (float*)d_out);
}

// Round 3
// 815.944 us; speedup vs baseline: 1.8170x; 1.8170x over previous
//
#include <hip/hip_runtime.h>

#define NN 100000
#define NE 3200000
#define NBUCK 782   // ceil(NN/128)
#define EPB 8192
#define NCB 391     // ceil(NE/EPB)

typedef __attribute__((ext_vector_type(8))) short bf16x8;
typedef __attribute__((ext_vector_type(4))) float f32x4;

__device__ __forceinline__ ushort f2bf(float f) {
  unsigned u = __builtin_bit_cast(unsigned, f);
  u = (u + 0x7FFFu + ((u >> 16) & 1u)) >> 16;
  return (ushort)u;
}
__device__ __forceinline__ float bf2f(ushort h) {
  return __builtin_bit_cast(float, ((unsigned)h) << 16);
}
__device__ __forceinline__ void gl2lds16(const void* g, void* s) {
  __builtin_amdgcn_global_load_lds((const __attribute__((address_space(1))) void*)g,
                                   (__attribute__((address_space(3))) void*)s, 16, 0, 0);
}

// ---------------- CSR build: two-pass block-local counting sort ----------------
// Pass 1: per-block LDS histogram of 782 coarse buckets (row>>7); no contended
// global atomics (306K adds spread over 782 addrs just for totals).
__global__ __launch_bounds__(256) void k_cnt(const int* __restrict__ row, int* __restrict__ ghist,
                                             int* __restrict__ bcnt) {
  __shared__ int h[NBUCK];
  int blk = blockIdx.x, tid = threadIdx.x;
  for (int i = tid; i < NBUCK; i += 256) h[i] = 0;
  __syncthreads();
  int lo = blk * EPB, hi = lo + EPB; if (hi > NE) hi = NE;
  for (int i = lo + tid * 4; i < hi; i += 1024) {
    int4 r = *(const int4*)(row + i);
    atomicAdd(&h[r.x >> 7], 1);
    atomicAdd(&h[r.y >> 7], 1);
    atomicAdd(&h[r.z >> 7], 1);
    atomicAdd(&h[r.w >> 7], 1);
  }
  __syncthreads();
  for (int i = tid; i < NBUCK; i += 256) {
    ghist[(size_t)i * NCB + blk] = h[i];
    if (h[i]) atomicAdd(&bcnt[i], h[i]);
  }
}

// scan of 782 bucket totals -> bucket bases (one small block)
__global__ __launch_bounds__(1024) void k_bscan(const int* __restrict__ bcnt, int* __restrict__ bbase) {
  __shared__ int s[1024];
  int t = threadIdx.x;
  s[t] = (t < NBUCK) ? bcnt[t] : 0;
  __syncthreads();
  for (int o = 1; o < 1024; o <<= 1) {
    int v = (t >= o) ? s[t - o] : 0;
    __syncthreads();
    s[t] += v;
    __syncthreads();
  }
  if (t < NBUCK) bbase[t] = t ? s[t - 1] : 0;
}

// per-bucket exclusive scan of the 391 per-block counts, + bucket base
__global__ __launch_bounds__(64) void k_scan3(int* __restrict__ ghist, const int* __restrict__ bbase) {
  int b = blockIdx.x, lane = threadIdx.x;
  int carry = bbase[b];
#pragma unroll
  for (int r = 0; r < 7; ++r) {     // 7*64 = 448 >= 391
    int idx = r * 64 + lane;
    int v = (idx < NCB) ? ghist[(size_t)b * NCB + idx] : 0;
    int s = v;
#pragma unroll
    for (int o = 1; o < 64; o <<= 1) { int t = __shfl_up(s, o, 64); if (lane >= o) s += t; }
    if (idx < NCB) ghist[(size_t)b * NCB + idx] = carry + s - v;
    carry += __shfl(s, 63, 64);
  }
}

// Pass 2: direct packed placement at pre-scanned offsets (LDS counters only)
__global__ __launch_bounds__(256) void k_place(const int* __restrict__ row, const int* __restrict__ col,
                                               const float* __restrict__ w, const int* __restrict__ ghist,
                                               int2* __restrict__ bdata) {
  __shared__ int offs[NBUCK];
  int blk = blockIdx.x, tid = threadIdx.x;
  for (int i = tid; i < NBUCK; i += 256) offs[i] = ghist[(size_t)i * NCB + blk];
  __syncthreads();
  int lo = blk * EPB, hi = lo + EPB; if (hi > NE) hi = NE;
  for (int i = lo + tid * 4; i < hi; i += 1024) {
    int4 r = *(const int4*)(row + i);
    int4 c = *(const int4*)(col + i);
    float4 ww = *(const float4*)(w + i);
    int p;
    p = atomicAdd(&offs[r.x >> 7], 1); bdata[p] = make_int2(((r.x & 127) << 17) | c.x, __float_as_int(ww.x));
    p = atomicAdd(&offs[r.y >> 7], 1); bdata[p] = make_int2(((r.y & 127) << 17) | c.y, __float_as_int(ww.y));
    p = atomicAdd(&offs[r.z >> 7], 1); bdata[p] = make_int2(((r.z & 127) << 17) | c.z, __float_as_int(ww.z));
    p = atomicAdd(&offs[r.w >> 7], 1); bdata[p] = make_int2(((r.w & 127) << 17) | c.w, __float_as_int(ww.w));
  }
}

// Pass 3: one block per bucket; LDS 128-row hist + scan -> rp, final row-sorted cw
__global__ __launch_bounds__(256) void k_bsort(const int* __restrict__ bcnt, const int* __restrict__ bbase,
                                               const int2* __restrict__ bdata, int2* __restrict__ cw,
                                               int* __restrict__ rp) {
  __shared__ int sc[128], lpos[128];
  int b = blockIdx.x, t = threadIdx.x;
  int n = bcnt[b], base = bbase[b];
  if (t < 128) sc[t] = 0;
  __syncthreads();
  for (int i = t; i < n; i += 256) {
    int r = bdata[(size_t)base + i].x >> 17;
    atomicAdd(&sc[r], 1);
  }
  __syncthreads();
  for (int o = 1; o < 128; o <<= 1) {
    int v = (t < 128 && t >= o) ? sc[t - o] : 0;
    __syncthreads();
    if (t < 128) sc[t] += v;
    __syncthreads();
  }
  if (t < 128) {
    int excl = t ? sc[t - 1] : 0;
    lpos[t] = excl;
    int grow = b * 128 + t;
    if (grow <= NN) rp[grow] = base + excl;
  }
  __syncthreads();
  for (int i = t; i < n; i += 256) {
    int2 e = bdata[(size_t)base + i];
    int r = e.x >> 17;
    int p = atomicAdd(&lpos[r], 1);
    cw[base + p] = make_int2(e.x & 0x1FFFF, e.y);
  }
}

// ---------------- weight prep: fold BN, transpose to [N][K], cast bf16 ----------------
__global__ __launch_bounds__(256) void k_prep(const float* __restrict__ W, const float* __restrict__ b,
                                              const float* __restrict__ g, const float* __restrict__ be,
                                              const float* __restrict__ m, const float* __restrict__ v,
                                              ushort* __restrict__ Wt, float* __restrict__ bp, int Ncol) {
  int j = blockIdx.x, k = threadIdx.x;
  float val = 0.f;
  if (j < Ncol) {
    float s = 1.f, t = 0.f;
    if (g) { s = g[j] * rsqrtf(v[j] + 1e-5f); t = be[j] - m[j] * s; }
    val = W[(size_t)k * Ncol + j] * s;
    if (k == 0) bp[j] = b[j] * s + t;
  } else if (k == 0) bp[j] = 0.f;
  Wt[(size_t)j * 256 + k] = f2bf(val);
}

// ---------------- x fp32 -> bf16 ----------------
__global__ __launch_bounds__(256) void k_f2bf8(const float* __restrict__ x, ushort* __restrict__ o) {
  size_t i = ((size_t)blockIdx.x * 256 + threadIdx.x) * 8;
  float4 u = *(const float4*)(x + i);
  float4 v = *(const float4*)(x + i + 4);
  ushort4 r0; r0.x = f2bf(u.x); r0.y = f2bf(u.y); r0.z = f2bf(u.z); r0.w = f2bf(u.w);
  ushort4 r1; r1.x = f2bf(v.x); r1.y = f2bf(v.y); r1.z = f2bf(v.z); r1.w = f2bf(v.w);
  *(ushort4*)(o + i) = r0;
  *(ushort4*)(o + i + 4) = r1;
}

// ---------------- bf16 MFMA GEMM: C[M x ncst] = A[M x 256] @ Wt^T, + bias, bf16 out ----------------
__global__ __launch_bounds__(256) void k_gemm(const ushort* __restrict__ A, const ushort* __restrict__ Bt,
                                              const float* __restrict__ bp, ushort* __restrict__ C,
                                              int M, int ldc, int ncst) {
  __shared__ ushort sA[128 * 64];
  __shared__ ushort sB[128 * 64];
  const int tid = threadIdx.x;
  const int lane = tid & 63;
  const int wave = tid >> 6;
  const int wm = wave >> 1, wn = wave & 1;
  const int bm = blockIdx.x, bn = blockIdx.y;

  f32x4 acc[4][4];
#pragma unroll
  for (int a = 0; a < 4; ++a)
#pragma unroll
    for (int b = 0; b < 4; ++b) acc[a][b] = (f32x4){0.f, 0.f, 0.f, 0.f};

  const char* Ab = (const char*)A;
  const char* Bb = (const char*)Bt;
  char* sAb = (char*)sA;
  char* sBb = (char*)sB;

  for (int kt = 0; kt < 4; ++kt) {
#pragma unroll
    for (int it = 0; it < 4; ++it) {
      int o = tid * 16 + it * 4096;
      int r = o >> 7, kb = o & 127;
      int ra = bm * 128 + r; if (ra >= M) ra = M - 1;
      gl2lds16(Ab + (size_t)ra * 512 + kt * 128 + kb, sAb + o);
      gl2lds16(Bb + (size_t)(bn * 128 + r) * 512 + kt * 128 + kb, sBb + o);
    }
    __syncthreads();
#pragma unroll
    for (int kk = 0; kk < 2; ++kk) {
      int kByte = kk * 64 + ((lane >> 4) << 4);
      bf16x8 af[4], bfr[4];
#pragma unroll
      for (int mi = 0; mi < 4; ++mi)
        af[mi] = *(const bf16x8*)(sAb + (wm * 64 + mi * 16 + (lane & 15)) * 128 + kByte);
#pragma unroll
      for (int ni = 0; ni < 4; ++ni)
        bfr[ni] = *(const bf16x8*)(sBb + (wn * 64 + ni * 16 + (lane & 15)) * 128 + kByte);
#pragma unroll
      for (int mi = 0; mi < 4; ++mi)
#pragma unroll
        for (int ni = 0; ni < 4; ++ni)
          acc[mi][ni] = __builtin_amdgcn_mfma_f32_16x16x32_bf16(af[mi], bfr[ni], acc[mi][ni], 0, 0, 0);
    }
    __syncthreads();
  }

  const int r0 = bm * 128 + wm * 64 + ((lane >> 4) << 2);
  const int c0 = bn * 128 + wn * 64 + (lane & 15);
#pragma unroll
  for (int ni = 0; ni < 4; ++ni) {
    int col = c0 + ni * 16;
    if (col >= ncst) continue;
    float bpv = bp[col];
#pragma unroll
    for (int mi = 0; mi < 4; ++mi)
#pragma unroll
      for (int i = 0; i < 4; ++i) {
        int row = r0 + mi * 16 + i;
        if (row < M) C[(size_t)row * ldc + col] = f2bf(acc[mi][ni][i] + bpv);
      }
  }
}

// ---------------- SpMM 256-dim: Y[i,:] = relu(sum w_e * H[col_e,:]), one wave/node ----------------
__global__ __launch_bounds__(256) void k_spmm256(const int* __restrict__ rp, const int2* __restrict__ cw,
                                                 const ushort* __restrict__ H, ushort* __restrict__ Y) {
  int node = blockIdx.x * 4 + (threadIdx.x >> 6);
  int lane = threadIdx.x & 63;
  int s = rp[node], e = rp[node + 1];
  float a0 = 0.f, a1 = 0.f, a2 = 0.f, a3 = 0.f;
  const ushort* Hl = H + (lane << 2);
  int i = s;
  for (; i + 4 <= e; i += 4) {
    int2 p0 = cw[i], p1 = cw[i + 1], p2 = cw[i + 2], p3 = cw[i + 3];
    ushort4 h0 = *(const ushort4*)(Hl + (size_t)p0.x * 256);
    ushort4 h1 = *(const ushort4*)(Hl + (size_t)p1.x * 256);
    ushort4 h2 = *(const ushort4*)(Hl + (size_t)p2.x * 256);
    ushort4 h3 = *(const ushort4*)(Hl + (size_t)p3.x * 256);
    float w0 = __int_as_float(p0.y), w1 = __int_as_float(p1.y);
    float w2 = __int_as_float(p2.y), w3 = __int_as_float(p3.y);
    a0 += w0 * bf2f(h0.x); a1 += w0 * bf2f(h0.y); a2 += w0 * bf2f(h0.z); a3 += w0 * bf2f(h0.w);
    a0 += w1 * bf2f(h1.x); a1 += w1 * bf2f(h1.y); a2 += w1 * bf2f(h1.z); a3 += w1 * bf2f(h1.w);
    a0 += w2 * bf2f(h2.x); a1 += w2 * bf2f(h2.y); a2 += w2 * bf2f(h2.z); a3 += w2 * bf2f(h2.w);
    a0 += w3 * bf2f(h3.x); a1 += w3 * bf2f(h3.y); a2 += w3 * bf2f(h3.z); a3 += w3 * bf2f(h3.w);
  }
  for (; i < e; ++i) {
    int2 p = cw[i];
    ushort4 h = *(const ushort4*)(Hl + (size_t)p.x * 256);
    float w = __int_as_float(p.y);
    a0 += w * bf2f(h.x); a1 += w * bf2f(h.y); a2 += w * bf2f(h.z); a3 += w * bf2f(h.w);
  }
  a0 = fmaxf(a0, 0.f); a1 = fmaxf(a1, 0.f); a2 = fmaxf(a2, 0.f); a3 = fmaxf(a3, 0.f);
  ushort4 o;
  o.x = f2bf(a0); o.y = f2bf(a1); o.z = f2bf(a2); o.w = f2bf(a3);
  *(ushort4*)(Y + (size_t)node * 256 + (lane << 2)) = o;
}

// ---------------- SpMM 64-dim + fused log_softmax, fp32 out ----------------
__global__ __launch_bounds__(256) void k_spmm64(const int* __restrict__ rp, const int2* __restrict__ cw,
                                                const ushort* __restrict__ H, float* __restrict__ out) {
  int node = blockIdx.x * 4 + (threadIdx.x >> 6);
  int lane = threadIdx.x & 63;
  int s = rp[node], e = rp[node + 1];
  float a = 0.f;
  int i = s;
  for (; i + 4 <= e; i += 4) {
    int2 p0 = cw[i], p1 = cw[i + 1], p2 = cw[i + 2], p3 = cw[i + 3];
    float h0 = bf2f(H[(size_t)p0.x * 64 + lane]);
    float h1 = bf2f(H[(size_t)p1.x * 64 + lane]);
    float h2 = bf2f(H[(size_t)p2.x * 64 + lane]);
    float h3 = bf2f(H[(size_t)p3.x * 64 + lane]);
    a += __int_as_float(p0.y) * h0 + __int_as_float(p1.y) * h1
       + __int_as_float(p2.y) * h2 + __int_as_float(p3.y) * h3;
  }
  for (; i < e; ++i) {
    int2 p = cw[i];
    a += __int_as_float(p.y) * bf2f(H[(size_t)p.x * 64 + lane]);
  }
  float mx = a;
#pragma unroll
  for (int o = 32; o > 0; o >>= 1) mx = fmaxf(mx, __shfl_xor(mx, o, 64));
  float ex = expf(a - mx);
  float sum = ex;
#pragma unroll
  for (int o = 32; o > 0; o >>= 1) sum += __shfl_xor(sum, o, 64);
  out[(size_t)node * 64 + lane] = (a - mx) - logf(sum);
}

extern "C" void kernel_launch(void* const* d_in, const int* in_sizes, int n_in,
                              void* d_out, int out_size, void* d_ws, size_t ws_size,
                              hipStream_t stream) {
  const float* x   = (const float*)d_in[0];
  const int* erow  = (const int*)d_in[1];
  const int* ecol  = (const int*)d_in[2];
  const float* ew  = (const float*)d_in[3];
  const float* W1  = (const float*)d_in[4];
  const float* b1  = (const float*)d_in[5];
  const float* g1  = (const float*)d_in[6];
  const float* be1 = (const float*)d_in[7];
  const float* m1  = (const float*)d_in[8];
  const float* v1  = (const float*)d_in[9];
  const float* W2  = (const float*)d_in[10];
  const float* b2  = (const float*)d_in[11];
  const float* g2  = (const float*)d_in[12];
  const float* be2 = (const float*)d_in[13];
  const float* m2  = (const float*)d_in[14];
  const float* v2  = (const float*)d_in[15];
  const float* W3  = (const float*)d_in[16];
  const float* b3  = (const float*)d_in[17];

  char* ws = (char*)d_ws;
  size_t off = 0;
  auto carve = [&](size_t bytes) -> void* {
    void* p = ws + off;
    off += (bytes + 511) & ~(size_t)511;
    return p;
  };
  int* bcnt   = (int*)carve((size_t)NBUCK * 4);
  int* bbase  = (int*)carve((size_t)NBUCK * 4);
  int* ghist  = (int*)carve((size_t)NBUCK * NCB * 4);
  int* rp     = (int*)carve((size_t)(NN + 1) * 4);
  int2* cw    = (int2*)carve((size_t)NE * 8);
  ushort* W1t = (ushort*)carve(256 * 256 * 2);
  ushort* W2t = (ushort*)carve(256 * 256 * 2);
  ushort* W3t = (ushort*)carve(128 * 256 * 2);
  float* bp1  = (float*)carve(256 * 4);
  float* bp2  = (float*)carve(256 * 4);
  float* bp3  = (float*)carve(128 * 4);
  ushort* bufA = (ushort*)carve((size_t)NN * 256 * 2);
  ushort* bufB = (ushort*)carve((size_t)NN * 256 * 2);
  ushort* bufC = (ushort*)carve((size_t)NN * 64 * 2);
  if (off > ws_size) return;

  // bucket scratch aliases bufA (not live until k_f2bf8): NE*8 = 25.6MB <= 51.2MB
  int2* bdata = (int2*)bufA;

  // CSR build (two-pass block-local counting sort, no contended global atomics)
  hipMemsetAsync(bcnt, 0, (size_t)NBUCK * 4, stream);
  k_cnt<<<NCB, 256, 0, stream>>>(erow, ghist, bcnt);
  k_bscan<<<1, 1024, 0, stream>>>(bcnt, bbase);
  k_scan3<<<NBUCK, 64, 0, stream>>>(ghist, bbase);
  k_place<<<NCB, 256, 0, stream>>>(erow, ecol, ew, ghist, bdata);
  k_bsort<<<NBUCK, 256, 0, stream>>>(bcnt, bbase, bdata, cw, rp);

  // weights (BN folded, transposed, bf16)
  k_prep<<<256, 256, 0, stream>>>(W1, b1, g1, be1, m1, v1, W1t, bp1, 256);
  k_prep<<<256, 256, 0, stream>>>(W2, b2, g2, be2, m2, v2, W2t, bp2, 256);
  k_prep<<<128, 256, 0, stream>>>(W3, b3, nullptr, nullptr, nullptr, nullptr, W3t, bp3, 64);

  // x -> bf16
  k_f2bf8<<<(NN * 256) / (256 * 8), 256, 0, stream>>>(x, bufA);

  const int gm = (NN + 127) / 128;
  // layer 1
  k_gemm<<<dim3(gm, 2), 256, 0, stream>>>(bufA, W1t, bp1, bufB, NN, 256, 256);
  k_spmm256<<<NN / 4, 256, 0, stream>>>(rp, cw, bufB, bufA);
  // layer 2
  k_gemm<<<dim3(gm, 2), 256, 0, stream>>>(bufA, W2t, bp2, bufB, NN, 256, 256);
  k_spmm256<<<NN / 4, 256, 0, stream>>>(rp, cw, bufB, bufA);
  // output layer
  k_gemm<<<dim3(gm, 1), 256, 0, stream>>>(bufA, W3t, bp3, bufC, NN, 64, 64);
  k_spmm64<<<NN / 4, 256, 0, stream>>>(rp, cw, bufC, (float*)d_out);
}